// Round 6
// baseline (770.999 us; speedup 1.0000x reference)
//
#include <hip/hip_runtime.h>

typedef __attribute__((ext_vector_type(8))) _Float16 half8;
typedef __attribute__((ext_vector_type(4))) _Float16 half4;
typedef __attribute__((ext_vector_type(4))) float f32x4;

constexpr int Bn = 4;
constexpr int Nn = 160;
constexpr int SEGN = Bn * Nn * Nn;        // 102400 segments
constexpr unsigned NEG_FLIP = 0x007FFFFFu; // flip(-inf)

__device__ __forceinline__ unsigned flipf(float f) {
  unsigned u = __float_as_uint(f);
  return (u & 0x80000000u) ? ~u : (u | 0x80000000u);
}
__device__ __forceinline__ float unflipf(unsigned s) {
  return __uint_as_float((s & 0x80000000u) ? (s ^ 0x80000000u) : ~s);
}

// ---------------- init segment buffer to flip(-inf) ----------------
__global__ void k_init(uint4* __restrict__ seg, int n4) {
  int i = blockIdx.x * blockDim.x + threadIdx.x;
  int stride = gridDim.x * blockDim.x;
  uint4 v = make_uint4(NEG_FLIP, NEG_FLIP, NEG_FLIP, NEG_FLIP);
  for (; i < n4; i += stride) seg[i] = v;
}

// ------- weight prepass: f32 [K][N] -> f16 chunk-blocked [k/32][N][32] -------
// (wf3: [512][16] -> [16][512] plain transpose)
__global__ void k_prep(const float* __restrict__ w1, const float* __restrict__ w2,
                       const float* __restrict__ w3, const float* __restrict__ wf1,
                       const float* __restrict__ wf2, const float* __restrict__ wf3,
                       _Float16* __restrict__ o1, _Float16* __restrict__ o2,
                       _Float16* __restrict__ o3, _Float16* __restrict__ of1,
                       _Float16* __restrict__ of2, _Float16* __restrict__ of3) {
  int t = blockIdx.x * 256 + threadIdx.x;
  const float* src; _Float16* dst; int N, local; bool is3 = false;
  if (t < 32768)       { src = w1;  dst = o1;  N = 256; local = t; }
  else if (t < 163840) { src = w2;  dst = o2;  N = 512; local = t - 32768; }
  else if (t < 425984) { src = w3;  dst = o3;  N = 512; local = t - 163840; }
  else if (t < 688128) { src = wf1; dst = of1; N = 512; local = t - 425984; }
  else if (t < 950272) { src = wf2; dst = of2; N = 512; local = t - 688128; }
  else if (t < 958464) { src = wf3; dst = of3; N = 16;  local = t - 950272; is3 = true; }
  else return;
  int k = local / N;
  int n = local - k * N;
  if (is3) dst[n * 512 + k] = (_Float16)src[local];
  else dst[(size_t)((k >> 5) * N + n) * 32 + (k & 31)] = (_Float16)src[local];
}

// ---------------- MFMA slice, B direct from global (L2-resident) ----------------
// A in LDS: f16 [64][K], rowB = 2K bytes, byte ^= ((row&7)<<4).
// W chunk-blocked global [c][NSTRIDE][32] f16. C0..C0+CN-1: weight chunk range
// (A's local chunk index starts at 0). nbase: global n offset of this slice.
template <int K, int C0, int CN, int NSTRIDE, int NT>
__device__ __forceinline__ void do_slice(const _Float16* __restrict__ wt,
                                         const char* a_base, int nbase,
                                         f32x4 (&acc)[4][NT], int tid) {
  constexpr int rowB = K * 2;
  const int w = tid >> 6, lane = tid & 63, ln15 = lane & 15, kg = lane >> 4;
  const char* wb = (const char*)wt;
#pragma unroll
  for (int c = 0; c < CN; ++c) {
    half8 a[4], b[NT];
#pragma unroll
    for (int nt = 0; nt < NT; ++nt) {
      int n = nbase + (w * NT + nt) * 16 + ln15;
      b[nt] = *(const half8*)(wb + (size_t)(C0 + c) * (NSTRIDE * 64) + n * 64 + kg * 16);
    }
#pragma unroll
    for (int mt = 0; mt < 4; ++mt) {
      int row = mt * 16 + ln15;
      int byte = (row * rowB + c * 64 + kg * 16) ^ ((row & 7) << 4);
      a[mt] = *(const half8*)(a_base + byte);
    }
#pragma unroll
    for (int mt = 0; mt < 4; ++mt)
#pragma unroll
      for (int nt = 0; nt < NT; ++nt)
        acc[mt][nt] = __builtin_amdgcn_mfma_f32_16x16x32_f16(a[mt], b[nt], acc[mt][nt], 0, 0, 0);
  }
}

template <int NT>
__device__ __forceinline__ void init_accn(const float* __restrict__ bias, int nbase,
                                          f32x4 (&acc)[4][NT], int tid) {
  const int w = tid >> 6, ln15 = tid & 15;
#pragma unroll
  for (int nt = 0; nt < NT; ++nt) {
    float bv = bias[nbase + (w * NT + nt) * 16 + ln15];
    f32x4 s = {bv, bv, bv, bv};
#pragma unroll
    for (int mt = 0; mt < 4; ++mt) acc[mt][nt] = s;
  }
}

// C layout: col = lane&15, row = (lane>>4)*4 + j  [m89 verified]
template <int NT, bool RELU>
__device__ __forceinline__ void store_hn(char* h, int rowB, int nbase,
                                         const f32x4 (&acc)[4][NT], int tid) {
  const int w = tid >> 6, lane = tid & 63, ln15 = lane & 15, kg = lane >> 4;
#pragma unroll
  for (int mt = 0; mt < 4; ++mt)
#pragma unroll
    for (int nt = 0; nt < NT; ++nt)
#pragma unroll
      for (int j = 0; j < 4; ++j) {
        int row = mt * 16 + kg * 4 + j;
        int n = nbase + (w * NT + nt) * 16 + ln15;
        float v = acc[mt][nt][j];
        if (RELU) v = fmaxf(v, 0.f);
        *(_Float16*)(h + ((row * rowB + n * 2) ^ ((row & 7) << 4))) = (_Float16)v;
      }
}

// ---------------- fused edge MLP (MFMA) + scatter-max ----------------
// 64 edges/block. LDS 64KB (h1 + half-buffer ping-pong) -> 2 blocks/CU.
// Layer3 acc stays in registers across the two layer2/layer3 half-phases.
__global__ __launch_bounds__(512, 2) void k_edge(
    const int* __restrict__ rel_type, const float* __restrict__ rel_error,
    const int* __restrict__ edge_pos, const int* __restrict__ rel_row,
    const float* __restrict__ type_tab, const float* __restrict__ pos_tab,
    const _Float16* __restrict__ w1t, const float* __restrict__ b1,
    const _Float16* __restrict__ w2t, const float* __restrict__ b2,
    const _Float16* __restrict__ w3t, const float* __restrict__ b3,
    unsigned* __restrict__ seg, int E) {
  __shared__ __align__(16) char smem[65536];
  __shared__ int rr[64];
  char* h1 = smem;            // [64][256] f16, rowB 512 (layer1 out, K of layer2)
  char* hh = smem + 32768;    // [64][256] f16, rowB 512 (h2 half, ping-pong)
  char* e  = smem + 32768;    // [64][128] f16, rowB 256 (dead after layer1)

  const int tid = threadIdx.x;
  const int e0 = blockIdx.x * 64;

  // ---- build e tile ----
  {
    int r = tid >> 3, c0 = (tid & 7) * 16;
    int re = min(e0 + r, E - 1);
    int rt = rel_type[re];
    int ep = edge_pos[re];
#pragma unroll
    for (int s = 0; s < 2; ++s) {
      half8 hv;
#pragma unroll
      for (int q = 0; q < 8; ++q) {
        int cc = c0 + s * 8 + q;
        float v = (cc < 120) ? (rt ? type_tab[rt * 120 + cc] : 0.f)
                             : rel_error[(size_t)re * 8 + (cc - 120)];
        v += pos_tab[ep * 128 + cc];
        hv[q] = (_Float16)v;
      }
      int byte = (r * 256 + (c0 + s * 8) * 2) ^ ((r & 7) << 4);
      *(half8*)(e + byte) = hv;
    }
    if (tid < 64) rr[tid] = rel_row[min(e0 + tid, E - 1)];
  }
  __syncthreads();

  {  // layer 1: [64x128]@[128x256] + relu -> h1
    f32x4 acc[4][2];
    init_accn<2>(b1, 0, acc, tid);
    do_slice<128, 0, 4, 256, 2>(w1t, e, 0, acc, tid);
    store_hn<2, true>(h1, 512, 0, acc, tid);
  }
  __syncthreads();   // h1 ready; e reads drained (hh region reusable)

  f32x4 acc3[4][4];
  init_accn<4>(b3, 0, acc3, tid);
#pragma unroll
  for (int hf = 0; hf < 2; ++hf) {
    // layer 2 half: h1 @ w2[:, hf*256 .. hf*256+255] -> hh (two 128-col substeps)
#pragma unroll
    for (int q = 0; q < 2; ++q) {
      f32x4 acc2[4][1];
      init_accn<1>(b2, hf * 256 + q * 128, acc2, tid);
      do_slice<256, 0, 8, 512, 1>(w2t, h1, hf * 256 + q * 128, acc2, tid);
      store_hn<1, true>(hh, 512, q * 128, acc2, tid);
    }
    __syncthreads();  // hh ready
    // layer 3 K-half: acc3 += hh @ w3[hf*256 .. , :]
    if (hf == 0) do_slice<256, 0, 8, 512, 4>(w3t, hh, 0, acc3, tid);
    else         do_slice<256, 8, 8, 512, 4>(w3t, hh, 0, acc3, tid);
    __syncthreads();  // hh reads drained before next half overwrites
  }

  {  // scatter-max into seg
    const int w = tid >> 6, lane = tid & 63, ln15 = lane & 15, kg = lane >> 4;
#pragma unroll
    for (int mt = 0; mt < 4; ++mt) {
      int rbase = mt * 16 + kg * 4;
      float m[4];
      int cur = rr[rbase];
#pragma unroll
      for (int nt = 0; nt < 4; ++nt) m[nt] = acc3[mt][nt][0];
#pragma unroll
      for (int j = 1; j < 4; ++j) {
        int rj = rr[rbase + j];
        if (rj == cur) {
#pragma unroll
          for (int nt = 0; nt < 4; ++nt) m[nt] = fmaxf(m[nt], acc3[mt][nt][j]);
        } else {
          unsigned* dst = seg + (size_t)cur * 512;
#pragma unroll
          for (int nt = 0; nt < 4; ++nt)
            atomicMax(dst + (w * 4 + nt) * 16 + ln15, flipf(m[nt]));
          cur = rj;
#pragma unroll
          for (int nt = 0; nt < 4; ++nt) m[nt] = acc3[mt][nt][j];
        }
      }
      unsigned* dst = seg + (size_t)cur * 512;
#pragma unroll
      for (int nt = 0; nt < 4; ++nt)
        atomicMax(dst + (w * 4 + nt) * 16 + ln15, flipf(m[nt]));
    }
  }
}

// ---- in-register epilogue: relu -> LN (shfl + 2-stage LDS) -> store f16 ----
__device__ __forceinline__ void epi_ln_store(f32x4 (&acc)[4][4], char* dst,
                                             float* st1, float* st2,
                                             float* stM, float* stR,
                                             const float* __restrict__ g,
                                             const float* __restrict__ be, int tid) {
  const int w = tid >> 6, lane = tid & 63, ln15 = lane & 15, kg = lane >> 4;
#pragma unroll
  for (int mt = 0; mt < 4; ++mt)
#pragma unroll
    for (int nt = 0; nt < 4; ++nt)
#pragma unroll
      for (int j = 0; j < 4; ++j) acc[mt][nt][j] = fmaxf(acc[mt][nt][j], 0.f);
#pragma unroll
  for (int mt = 0; mt < 4; ++mt)
#pragma unroll
    for (int j = 0; j < 4; ++j) {
      float a = 0.f, b = 0.f;
#pragma unroll
      for (int nt = 0; nt < 4; ++nt) { float v = acc[mt][nt][j]; a += v; b += v * v; }
#pragma unroll
      for (int m = 1; m < 16; m <<= 1) { a += __shfl_xor(a, m); b += __shfl_xor(b, m); }
      if (ln15 == 0) {
        int r = mt * 16 + kg * 4 + j;
        st1[w * 64 + r] = a;
        st2[w * 64 + r] = b;
      }
    }
  __syncthreads();
  if (tid < 64) {
    float a = 0.f, b = 0.f;
#pragma unroll
    for (int ww = 0; ww < 8; ++ww) { a += st1[ww * 64 + tid]; b += st2[ww * 64 + tid]; }
    float mean = a * (1.f / 512.f);
    float var = b * (1.f / 512.f) - mean * mean;
    stM[tid] = mean;
    stR[tid] = rsqrtf(var + 1e-5f);
  }
  __syncthreads();
  float gv[4], bv[4];
#pragma unroll
  for (int nt = 0; nt < 4; ++nt) {
    int n = (w * 4 + nt) * 16 + ln15;
    gv[nt] = g[n]; bv[nt] = be[n];
  }
#pragma unroll
  for (int mt = 0; mt < 4; ++mt)
#pragma unroll
    for (int j = 0; j < 4; ++j) {
      int r = mt * 16 + kg * 4 + j;
      float mean = stM[r], rs = stR[r];
#pragma unroll
      for (int nt = 0; nt < 4; ++nt) {
        int n = (w * 4 + nt) * 16 + ln15;
        float v = (acc[mt][nt][j] - mean) * rs * gv[nt] + bv[nt];
        *(_Float16*)(dst + ((r * 1024 + n * 2) ^ ((r & 7) << 4))) = (_Float16)v;
      }
    }
  __syncthreads();
}

// ---------------- fused FC: seg+dist -> LN -> fc1 -> LN -> fc2 -> LN -> fc3 ----------------
// launch_bounds(512, 2): 2 blocks/CU -> 128-VGPR budget (r4: (512,4) => 64 VGPR, spilled).
__global__ __launch_bounds__(512, 2) void k_fc(
    const unsigned* __restrict__ segin, const int* __restrict__ dist,
    const float* __restrict__ dist_tab,
    const float* __restrict__ g1, const float* __restrict__ be1,
    const _Float16* __restrict__ wf1t, const float* __restrict__ bf1,
    const float* __restrict__ g2, const float* __restrict__ be2,
    const _Float16* __restrict__ wf2t, const float* __restrict__ bf2,
    const float* __restrict__ g3, const float* __restrict__ be3,
    const _Float16* __restrict__ wf3t, const float* __restrict__ bf3,
    float* __restrict__ x3) {
  __shared__ __align__(16) char bufA[65536];  // [64][512] f16, rowB 1024
  __shared__ float st1[512], st2[512];
  __shared__ float stM[64], stR[64];

  const int tid = threadIdx.x;
  const int r0 = blockIdx.x * 64;

  // ---- prologue: seg + dist emb -> relu -> LN1 -> bufA (f16, swizzled) ----
  {
    const int r = tid >> 3, cp = tid & 7;
    const int gr = r0 + r;
    int di = dist[gr];
    const float* dt = dist_tab + (size_t)di * 512;
    float s1 = 0.f, s2 = 0.f;
#pragma unroll
    for (int i = 0; i < 16; ++i) {
      int c = cp * 64 + i * 4;
      uint4 sv = *(const uint4*)(segin + (size_t)gr * 512 + c);
      float v0 = (sv.x == NEG_FLIP) ? 0.f : unflipf(sv.x);
      float v1 = (sv.y == NEG_FLIP) ? 0.f : unflipf(sv.y);
      float v2 = (sv.z == NEG_FLIP) ? 0.f : unflipf(sv.z);
      float v3 = (sv.w == NEG_FLIP) ? 0.f : unflipf(sv.w);
      if (di) { v0 += dt[c]; v1 += dt[c + 1]; v2 += dt[c + 2]; v3 += dt[c + 3]; }
      v0 = fmaxf(v0, 0.f); v1 = fmaxf(v1, 0.f); v2 = fmaxf(v2, 0.f); v3 = fmaxf(v3, 0.f);
      s1 += v0 + v1 + v2 + v3;
      s2 += v0 * v0 + v1 * v1 + v2 * v2 + v3 * v3;
      half4 hv = {(_Float16)v0, (_Float16)v1, (_Float16)v2, (_Float16)v3};
      *(half4*)(bufA + ((r * 1024 + c * 2) ^ ((r & 7) << 4))) = hv;
    }
#pragma unroll
    for (int o = 4; o > 0; o >>= 1) { s1 += __shfl_down(s1, o); s2 += __shfl_down(s2, o); }
    if (cp == 0) {
      float mean = s1 * (1.f / 512.f);
      float var = s2 * (1.f / 512.f) - mean * mean;
      stM[r] = mean;
      stR[r] = rsqrtf(var + 1e-5f);
    }
    __syncthreads();
    float mean = stM[r], rs = stR[r];
#pragma unroll
    for (int i = 0; i < 16; ++i) {
      int c = cp * 64 + i * 4;
      int byte = (r * 1024 + c * 2) ^ ((r & 7) << 4);
      half4 hv = *(half4*)(bufA + byte);
      float4 g4 = *(const float4*)(g1 + c);
      float4 b4 = *(const float4*)(be1 + c);
      half4 ov = {(_Float16)(((float)hv[0] - mean) * rs * g4.x + b4.x),
                  (_Float16)(((float)hv[1] - mean) * rs * g4.y + b4.y),
                  (_Float16)(((float)hv[2] - mean) * rs * g4.z + b4.z),
                  (_Float16)(((float)hv[3] - mean) * rs * g4.w + b4.w)};
      *(half4*)(bufA + byte) = ov;
    }
  }
  __syncthreads();

  {  // fc1: bufA @ wf1 -> LN2 -> bufA (in-place)
    f32x4 acc[4][4];
    init_accn<4>(bf1, 0, acc, tid);
    do_slice<512, 0, 16, 512, 4>(wf1t, bufA, 0, acc, tid);
    epi_ln_store(acc, bufA, st1, st2, stM, stR, g2, be2, tid);
  }
  {  // fc2: bufA @ wf2 -> LN3 -> bufA (in-place)
    f32x4 acc[4][4];
    init_accn<4>(bf2, 0, acc, tid);
    do_slice<512, 0, 16, 512, 4>(wf2t, bufA, 0, acc, tid);
    epi_ln_store(acc, bufA, st1, st2, stM, stR, g3, be3, tid);
  }
  {  // fc3: bufA @ wf3 [64x512]@[512x16], 4-wave M-split, direct store
    const int w = tid >> 6, lane = tid & 63, ln15 = lane & 15, kg = lane >> 4;
    if (w < 4) {
      f32x4 acc3 = {0.f, 0.f, 0.f, 0.f};
#pragma unroll
      for (int c = 0; c < 16; ++c) {
        half8 b = *(const half8*)((const char*)wf3t + ln15 * 1024 + c * 64 + kg * 16);
        int row = w * 16 + ln15;
        half8 a = *(const half8*)(bufA + ((row * 1024 + c * 64 + kg * 16) ^ ((row & 7) << 4)));
        acc3 = __builtin_amdgcn_mfma_f32_16x16x32_f16(a, b, acc3, 0, 0, 0);
      }
#pragma unroll
      for (int j = 0; j < 4; ++j)
        x3[(size_t)(r0 + w * 16 + kg * 4 + j) * 16 + ln15] = acc3[j] + bf3[ln15];
    }
  }
}

// ---------------- triu mask + symmetrize ----------------
__global__ void k_sym(const float* __restrict__ x3, float* __restrict__ out) {
  int t = blockIdx.x * 256 + threadIdx.x;
  if (t >= SEGN * 4) return;
  int q = t & 3;
  int cell = t >> 2;
  int j = cell % Nn;
  int tmp = cell / Nn;
  int i = tmp % Nn;
  int b = tmp / Nn;
  float4 v = make_float4(0.f, 0.f, 0.f, 0.f);
  if (i <= j) v = *(const float4*)&x3[(size_t)cell * 16 + q * 4];
  if (j <= i) {
    int cell2 = (b * Nn + j) * Nn + i;
    float4 u = *(const float4*)&x3[(size_t)cell2 * 16 + q * 4];
    v.x += u.x; v.y += u.y; v.z += u.z; v.w += u.w;
  }
  *(float4*)&out[(size_t)t * 4] = v;
}

extern "C" void kernel_launch(void* const* d_in, const int* in_sizes, int n_in,
                              void* d_out, int out_size, void* d_ws, size_t ws_size,
                              hipStream_t stream) {
  const int*   rel_type  = (const int*)d_in[0];
  const float* rel_error = (const float*)d_in[1];
  const int*   edge_pos  = (const int*)d_in[2];
  const int*   dist      = (const int*)d_in[3];
  const int*   rel_row   = (const int*)d_in[4];
  const float* type_tab = (const float*)d_in[8];
  const float* pos_tab  = (const float*)d_in[9];
  const float* dist_tab = (const float*)d_in[10];
  const float* w1 = (const float*)d_in[11]; const float* b1 = (const float*)d_in[12];
  const float* w2 = (const float*)d_in[13]; const float* b2 = (const float*)d_in[14];
  const float* w3 = (const float*)d_in[15]; const float* b3 = (const float*)d_in[16];
  const float* g1 = (const float*)d_in[17]; const float* be1 = (const float*)d_in[18];
  const float* wf1 = (const float*)d_in[19]; const float* bf1 = (const float*)d_in[20];
  const float* g2 = (const float*)d_in[21]; const float* be2 = (const float*)d_in[22];
  const float* wf2 = (const float*)d_in[23]; const float* bf2 = (const float*)d_in[24];
  const float* g3 = (const float*)d_in[25]; const float* be3 = (const float*)d_in[26];
  const float* wf3 = (const float*)d_in[27]; const float* bf3 = (const float*)d_in[28];

  const int E = in_sizes[0];
  const size_t seg_bytes = (size_t)SEGN * 512 * 4;     // 209.7 MB
  const size_t x3_bytes  = (size_t)SEGN * 16 * 4;      // 6.55 MB
  const size_t wt_elems  = 32768 + 131072 + 262144 * 3 + 8192;
  if (ws_size < seg_bytes + x3_bytes + wt_elems * 2) return;

  unsigned*  seg = (unsigned*)d_ws;
  float*     x3  = (float*)((char*)d_ws + seg_bytes);
  _Float16*  w1t = (_Float16*)((char*)d_ws + seg_bytes + x3_bytes);
  _Float16*  w2t = w1t + 32768;
  _Float16*  w3t = w2t + 131072;
  _Float16*  wf1t = w3t + 262144;
  _Float16*  wf2t = wf1t + 262144;
  _Float16*  wf3t = wf2t + 262144;
  float*     out = (float*)d_out;

  k_prep<<<3744, 256, 0, stream>>>(w1, w2, w3, wf1, wf2, wf3,
                                   w1t, w2t, w3t, wf1t, wf2t, wf3t);
  k_init<<<2048, 256, 0, stream>>>((uint4*)seg, SEGN * 512 / 4);
  k_edge<<<(E + 63) / 64, 512, 0, stream>>>(rel_type, rel_error, edge_pos, rel_row,
                                            type_tab, pos_tab, w1t, b1, w2t, b2, w3t, b3,
                                            seg, E);
  k_fc<<<SEGN / 64, 512, 0, stream>>>(seg, dist, dist_tab,
                                      g1, be1, wf1t, bf1,
                                      g2, be2, wf2t, bf2,
                                      g3, be3, wf3t, bf3, x3);
  k_sym<<<(SEGN * 4 + 255) / 256, 256, 0, stream>>>(x3, out);
}

// Round 7
// 743.631 us; speedup vs baseline: 1.0368x; 1.0368x over previous
//
#include <hip/hip_runtime.h>

typedef __attribute__((ext_vector_type(8))) _Float16 half8;
typedef __attribute__((ext_vector_type(4))) _Float16 half4;
typedef __attribute__((ext_vector_type(4))) float f32x4;

constexpr int Bn = 4;
constexpr int Nn = 160;
constexpr int SEGN = Bn * Nn * Nn;        // 102400 segments
constexpr unsigned NEG_FLIP = 0x007FFFFFu; // flip(-inf)

__device__ __forceinline__ unsigned flipf(float f) {
  unsigned u = __float_as_uint(f);
  return (u & 0x80000000u) ? ~u : (u | 0x80000000u);
}
__device__ __forceinline__ float unflipf(unsigned s) {
  return __uint_as_float((s & 0x80000000u) ? (s ^ 0x80000000u) : ~s);
}

// ---------------- init segment buffer to flip(-inf) ----------------
__global__ void k_init(uint4* __restrict__ seg, int n4) {
  int i = blockIdx.x * blockDim.x + threadIdx.x;
  int stride = gridDim.x * blockDim.x;
  uint4 v = make_uint4(NEG_FLIP, NEG_FLIP, NEG_FLIP, NEG_FLIP);
  for (; i < n4; i += stride) seg[i] = v;
}

// ------- weight prepass: f32 [K][N] -> f16 chunk-blocked [k/32][N][32] -------
// (wf3: [512][16] -> [16][512] plain transpose)
__global__ void k_prep(const float* __restrict__ w1, const float* __restrict__ w2,
                       const float* __restrict__ w3, const float* __restrict__ wf1,
                       const float* __restrict__ wf2, const float* __restrict__ wf3,
                       _Float16* __restrict__ o1, _Float16* __restrict__ o2,
                       _Float16* __restrict__ o3, _Float16* __restrict__ of1,
                       _Float16* __restrict__ of2, _Float16* __restrict__ of3) {
  int t = blockIdx.x * 256 + threadIdx.x;
  const float* src; _Float16* dst; int N, local; bool is3 = false;
  if (t < 32768)       { src = w1;  dst = o1;  N = 256; local = t; }
  else if (t < 163840) { src = w2;  dst = o2;  N = 512; local = t - 32768; }
  else if (t < 425984) { src = w3;  dst = o3;  N = 512; local = t - 163840; }
  else if (t < 688128) { src = wf1; dst = of1; N = 512; local = t - 425984; }
  else if (t < 950272) { src = wf2; dst = of2; N = 512; local = t - 688128; }
  else if (t < 958464) { src = wf3; dst = of3; N = 16;  local = t - 950272; is3 = true; }
  else return;
  int k = local / N;
  int n = local - k * N;
  if (is3) dst[n * 512 + k] = (_Float16)src[local];
  else dst[(size_t)((k >> 5) * N + n) * 32 + (k & 31)] = (_Float16)src[local];
}

// ------- MFMA layer, B direct from global (L2), depth-2 register prefetch -------
// A in LDS: f16 [64][K], rowB = 2K bytes, byte ^= ((row&7)<<4).
// W chunk-blocked global [c][N][32] f16. All prefetch slots statically indexed.
template <int K, int NT>
__device__ __forceinline__ void do_layer_pf(const _Float16* __restrict__ wt,
                                            const char* a_base,
                                            f32x4 (&acc)[4][NT], int tid) {
  constexpr int C = K / 32;        // 4 / 8 / 16 (even)
  constexpr int N = NT * 128;
  constexpr int rowB = K * 2;
  const int w = tid >> 6, lane = tid & 63, ln15 = lane & 15, kg = lane >> 4;
  const char* wb = (const char*)wt + kg * 16;

  half8 b0[NT], b1[NT];
#pragma unroll
  for (int nt = 0; nt < NT; ++nt) {
    int n = (w * NT + nt) * 16 + ln15;
    b0[nt] = *(const half8*)(wb + (size_t)0 * (N * 64) + n * 64);
    b1[nt] = *(const half8*)(wb + (size_t)1 * (N * 64) + n * 64);
  }
#pragma unroll
  for (int c = 0; c < C; c += 2) {
    half8 t0[NT], t1[NT];
    if (c + 2 < C) {
#pragma unroll
      for (int nt = 0; nt < NT; ++nt) {
        int n = (w * NT + nt) * 16 + ln15;
        t0[nt] = *(const half8*)(wb + (size_t)(c + 2) * (N * 64) + n * 64);
      }
    }
    {  // chunk c with b0
      half8 a[4];
#pragma unroll
      for (int mt = 0; mt < 4; ++mt) {
        int row = mt * 16 + ln15;
        int byte = (row * rowB + c * 64 + kg * 16) ^ ((row & 7) << 4);
        a[mt] = *(const half8*)(a_base + byte);
      }
#pragma unroll
      for (int mt = 0; mt < 4; ++mt)
#pragma unroll
        for (int nt = 0; nt < NT; ++nt)
          acc[mt][nt] = __builtin_amdgcn_mfma_f32_16x16x32_f16(a[mt], b0[nt], acc[mt][nt], 0, 0, 0);
    }
    if (c + 3 < C) {
#pragma unroll
      for (int nt = 0; nt < NT; ++nt) {
        int n = (w * NT + nt) * 16 + ln15;
        t1[nt] = *(const half8*)(wb + (size_t)(c + 3) * (N * 64) + n * 64);
      }
    }
    {  // chunk c+1 with b1
      half8 a[4];
#pragma unroll
      for (int mt = 0; mt < 4; ++mt) {
        int row = mt * 16 + ln15;
        int byte = (row * rowB + (c + 1) * 64 + kg * 16) ^ ((row & 7) << 4);
        a[mt] = *(const half8*)(a_base + byte);
      }
#pragma unroll
      for (int mt = 0; mt < 4; ++mt)
#pragma unroll
        for (int nt = 0; nt < NT; ++nt)
          acc[mt][nt] = __builtin_amdgcn_mfma_f32_16x16x32_f16(a[mt], b1[nt], acc[mt][nt], 0, 0, 0);
    }
#pragma unroll
    for (int nt = 0; nt < NT; ++nt) { b0[nt] = t0[nt]; b1[nt] = t1[nt]; }
  }
}

// ---------------- MFMA slice (non-prefetch, used by k_fc) ----------------
template <int K, int C0, int CN, int NSTRIDE, int NT>
__device__ __forceinline__ void do_slice(const _Float16* __restrict__ wt,
                                         const char* a_base, int nbase,
                                         f32x4 (&acc)[4][NT], int tid) {
  constexpr int rowB = K * 2;
  const int w = tid >> 6, lane = tid & 63, ln15 = lane & 15, kg = lane >> 4;
  const char* wb = (const char*)wt;
#pragma unroll
  for (int c = 0; c < CN; ++c) {
    half8 a[4], b[NT];
#pragma unroll
    for (int nt = 0; nt < NT; ++nt) {
      int n = nbase + (w * NT + nt) * 16 + ln15;
      b[nt] = *(const half8*)(wb + (size_t)(C0 + c) * (NSTRIDE * 64) + n * 64 + kg * 16);
    }
#pragma unroll
    for (int mt = 0; mt < 4; ++mt) {
      int row = mt * 16 + ln15;
      int byte = (row * rowB + c * 64 + kg * 16) ^ ((row & 7) << 4);
      a[mt] = *(const half8*)(a_base + byte);
    }
#pragma unroll
    for (int mt = 0; mt < 4; ++mt)
#pragma unroll
      for (int nt = 0; nt < NT; ++nt)
        acc[mt][nt] = __builtin_amdgcn_mfma_f32_16x16x32_f16(a[mt], b[nt], acc[mt][nt], 0, 0, 0);
  }
}

template <int NT>
__device__ __forceinline__ void init_accn(const float* __restrict__ bias, int nbase,
                                          f32x4 (&acc)[4][NT], int tid) {
  const int w = tid >> 6, ln15 = tid & 15;
#pragma unroll
  for (int nt = 0; nt < NT; ++nt) {
    float bv = bias[nbase + (w * NT + nt) * 16 + ln15];
    f32x4 s = {bv, bv, bv, bv};
#pragma unroll
    for (int mt = 0; mt < 4; ++mt) acc[mt][nt] = s;
  }
}

// C layout: col = lane&15, row = (lane>>4)*4 + j  [m89 verified]
template <int NT, bool RELU>
__device__ __forceinline__ void store_hn(char* h, int rowB, int nbase,
                                         const f32x4 (&acc)[4][NT], int tid) {
  const int w = tid >> 6, lane = tid & 63, ln15 = lane & 15, kg = lane >> 4;
#pragma unroll
  for (int mt = 0; mt < 4; ++mt)
#pragma unroll
    for (int nt = 0; nt < NT; ++nt)
#pragma unroll
      for (int j = 0; j < 4; ++j) {
        int row = mt * 16 + kg * 4 + j;
        int n = nbase + (w * NT + nt) * 16 + ln15;
        float v = acc[mt][nt][j];
        if (RELU) v = fmaxf(v, 0.f);
        *(_Float16*)(h + ((row * rowB + n * 2) ^ ((row & 7) << 4))) = (_Float16)v;
      }
}

// ---------------- fused edge MLP (MFMA, prefetched) + scatter-max ----------------
// r5 structure (sequential layers, 96.5 KB LDS, 1 block/CU) + launch_bounds(512,1)
// so the compiler gets the full VGPR budget for the prefetch ring (r5: 88 regs).
__global__ __launch_bounds__(512, 1) void k_edge(
    const int* __restrict__ rel_type, const float* __restrict__ rel_error,
    const int* __restrict__ edge_pos, const int* __restrict__ rel_row,
    const float* __restrict__ type_tab, const float* __restrict__ pos_tab,
    const _Float16* __restrict__ w1t, const float* __restrict__ b1,
    const _Float16* __restrict__ w2t, const float* __restrict__ b2,
    const _Float16* __restrict__ w3t, const float* __restrict__ b3,
    unsigned* __restrict__ seg, int E) {
  __shared__ __align__(16) char smem[98304];
  __shared__ int rr[64];
  char* h1 = smem;            // [64][256] f16, rowB 512
  char* h2 = smem + 32768;    // [64][512] f16, rowB 1024
  char* e  = smem + 32768;    // [64][128] f16, rowB 256 (dead before h2 written)

  const int tid = threadIdx.x;
  const int e0 = blockIdx.x * 64;

  // ---- build e tile ----
  {
    int r = tid >> 3, c0 = (tid & 7) * 16;
    int re = min(e0 + r, E - 1);
    int rt = rel_type[re];
    int ep = edge_pos[re];
#pragma unroll
    for (int s = 0; s < 2; ++s) {
      half8 hv;
#pragma unroll
      for (int q = 0; q < 8; ++q) {
        int cc = c0 + s * 8 + q;
        float v = (cc < 120) ? (rt ? type_tab[rt * 120 + cc] : 0.f)
                             : rel_error[(size_t)re * 8 + (cc - 120)];
        v += pos_tab[ep * 128 + cc];
        hv[q] = (_Float16)v;
      }
      int byte = (r * 256 + (c0 + s * 8) * 2) ^ ((r & 7) << 4);
      *(half8*)(e + byte) = hv;
    }
    if (tid < 64) rr[tid] = rel_row[min(e0 + tid, E - 1)];
  }
  __syncthreads();

  {  // layer 1: [64x128]@[128x256] + relu -> h1
    f32x4 acc[4][2];
    init_accn<2>(b1, 0, acc, tid);
    do_layer_pf<128, 2>(w1t, e, acc, tid);
    store_hn<2, true>(h1, 512, 0, acc, tid);
  }
  __syncthreads();
  {  // layer 2: [64x256]@[256x512] + relu -> h2 (overwrites e region, reads drained)
    f32x4 acc[4][4];
    init_accn<4>(b2, 0, acc, tid);
    do_layer_pf<256, 4>(w2t, h1, acc, tid);
    store_hn<4, true>(h2, 1024, 0, acc, tid);
  }
  __syncthreads();
  {  // layer 3: [64x512]@[512x512] -> scatter-max
    f32x4 acc[4][4];
    init_accn<4>(b3, 0, acc, tid);
    do_layer_pf<512, 4>(w3t, h2, acc, tid);

    const int w = tid >> 6, lane = tid & 63, ln15 = lane & 15, kg = lane >> 4;
#pragma unroll
    for (int mt = 0; mt < 4; ++mt) {
      int rbase = mt * 16 + kg * 4;
      float m[4];
      int cur = rr[rbase];
#pragma unroll
      for (int nt = 0; nt < 4; ++nt) m[nt] = acc[mt][nt][0];
#pragma unroll
      for (int j = 1; j < 4; ++j) {
        int rj = rr[rbase + j];
        if (rj == cur) {
#pragma unroll
          for (int nt = 0; nt < 4; ++nt) m[nt] = fmaxf(m[nt], acc[mt][nt][j]);
        } else {
          unsigned* dst = seg + (size_t)cur * 512;
#pragma unroll
          for (int nt = 0; nt < 4; ++nt)
            atomicMax(dst + (w * 4 + nt) * 16 + ln15, flipf(m[nt]));
          cur = rj;
#pragma unroll
          for (int nt = 0; nt < 4; ++nt) m[nt] = acc[mt][nt][j];
        }
      }
      unsigned* dst = seg + (size_t)cur * 512;
#pragma unroll
      for (int nt = 0; nt < 4; ++nt)
        atomicMax(dst + (w * 4 + nt) * 16 + ln15, flipf(m[nt]));
    }
  }
}

// ---- in-register epilogue: relu -> LN (shfl + 2-stage LDS) -> store f16 ----
__device__ __forceinline__ void epi_ln_store(f32x4 (&acc)[4][4], char* dst,
                                             float* st1, float* st2,
                                             float* stM, float* stR,
                                             const float* __restrict__ g,
                                             const float* __restrict__ be, int tid) {
  const int w = tid >> 6, lane = tid & 63, ln15 = lane & 15, kg = lane >> 4;
#pragma unroll
  for (int mt = 0; mt < 4; ++mt)
#pragma unroll
    for (int nt = 0; nt < 4; ++nt)
#pragma unroll
      for (int j = 0; j < 4; ++j) acc[mt][nt][j] = fmaxf(acc[mt][nt][j], 0.f);
#pragma unroll
  for (int mt = 0; mt < 4; ++mt)
#pragma unroll
    for (int j = 0; j < 4; ++j) {
      float a = 0.f, b = 0.f;
#pragma unroll
      for (int nt = 0; nt < 4; ++nt) { float v = acc[mt][nt][j]; a += v; b += v * v; }
#pragma unroll
      for (int m = 1; m < 16; m <<= 1) { a += __shfl_xor(a, m); b += __shfl_xor(b, m); }
      if (ln15 == 0) {
        int r = mt * 16 + kg * 4 + j;
        st1[w * 64 + r] = a;
        st2[w * 64 + r] = b;
      }
    }
  __syncthreads();
  if (tid < 64) {
    float a = 0.f, b = 0.f;
#pragma unroll
    for (int ww = 0; ww < 8; ++ww) { a += st1[ww * 64 + tid]; b += st2[ww * 64 + tid]; }
    float mean = a * (1.f / 512.f);
    float var = b * (1.f / 512.f) - mean * mean;
    stM[tid] = mean;
    stR[tid] = rsqrtf(var + 1e-5f);
  }
  __syncthreads();
  float gv[4], bv[4];
#pragma unroll
  for (int nt = 0; nt < 4; ++nt) {
    int n = (w * 4 + nt) * 16 + ln15;
    gv[nt] = g[n]; bv[nt] = be[n];
  }
#pragma unroll
  for (int mt = 0; mt < 4; ++mt)
#pragma unroll
    for (int j = 0; j < 4; ++j) {
      int r = mt * 16 + kg * 4 + j;
      float mean = stM[r], rs = stR[r];
#pragma unroll
      for (int nt = 0; nt < 4; ++nt) {
        int n = (w * 4 + nt) * 16 + ln15;
        float v = (acc[mt][nt][j] - mean) * rs * gv[nt] + bv[nt];
        *(_Float16*)(dst + ((r * 1024 + n * 2) ^ ((r & 7) << 4))) = (_Float16)v;
      }
    }
  __syncthreads();
}

// ---------------- fused FC: seg+dist -> LN -> fc1 -> LN -> fc2 -> LN -> fc3 ----------------
// launch_bounds(512, 2): 2 blocks/CU -> 128-VGPR budget (r4: (512,4) => 64 VGPR, spilled).
__global__ __launch_bounds__(512, 2) void k_fc(
    const unsigned* __restrict__ segin, const int* __restrict__ dist,
    const float* __restrict__ dist_tab,
    const float* __restrict__ g1, const float* __restrict__ be1,
    const _Float16* __restrict__ wf1t, const float* __restrict__ bf1,
    const float* __restrict__ g2, const float* __restrict__ be2,
    const _Float16* __restrict__ wf2t, const float* __restrict__ bf2,
    const float* __restrict__ g3, const float* __restrict__ be3,
    const _Float16* __restrict__ wf3t, const float* __restrict__ bf3,
    float* __restrict__ x3) {
  __shared__ __align__(16) char bufA[65536];  // [64][512] f16, rowB 1024
  __shared__ float st1[512], st2[512];
  __shared__ float stM[64], stR[64];

  const int tid = threadIdx.x;
  const int r0 = blockIdx.x * 64;

  // ---- prologue: seg + dist emb -> relu -> LN1 -> bufA (f16, swizzled) ----
  {
    const int r = tid >> 3, cp = tid & 7;
    const int gr = r0 + r;
    int di = dist[gr];
    const float* dt = dist_tab + (size_t)di * 512;
    float s1 = 0.f, s2 = 0.f;
#pragma unroll
    for (int i = 0; i < 16; ++i) {
      int c = cp * 64 + i * 4;
      uint4 sv = *(const uint4*)(segin + (size_t)gr * 512 + c);
      float v0 = (sv.x == NEG_FLIP) ? 0.f : unflipf(sv.x);
      float v1 = (sv.y == NEG_FLIP) ? 0.f : unflipf(sv.y);
      float v2 = (sv.z == NEG_FLIP) ? 0.f : unflipf(sv.z);
      float v3 = (sv.w == NEG_FLIP) ? 0.f : unflipf(sv.w);
      if (di) { v0 += dt[c]; v1 += dt[c + 1]; v2 += dt[c + 2]; v3 += dt[c + 3]; }
      v0 = fmaxf(v0, 0.f); v1 = fmaxf(v1, 0.f); v2 = fmaxf(v2, 0.f); v3 = fmaxf(v3, 0.f);
      s1 += v0 + v1 + v2 + v3;
      s2 += v0 * v0 + v1 * v1 + v2 * v2 + v3 * v3;
      half4 hv = {(_Float16)v0, (_Float16)v1, (_Float16)v2, (_Float16)v3};
      *(half4*)(bufA + ((r * 1024 + c * 2) ^ ((r & 7) << 4))) = hv;
    }
#pragma unroll
    for (int o = 4; o > 0; o >>= 1) { s1 += __shfl_down(s1, o); s2 += __shfl_down(s2, o); }
    if (cp == 0) {
      float mean = s1 * (1.f / 512.f);
      float var = s2 * (1.f / 512.f) - mean * mean;
      stM[r] = mean;
      stR[r] = rsqrtf(var + 1e-5f);
    }
    __syncthreads();
    float mean = stM[r], rs = stR[r];
#pragma unroll
    for (int i = 0; i < 16; ++i) {
      int c = cp * 64 + i * 4;
      int byte = (r * 1024 + c * 2) ^ ((r & 7) << 4);
      half4 hv = *(half4*)(bufA + byte);
      float4 g4 = *(const float4*)(g1 + c);
      float4 b4 = *(const float4*)(be1 + c);
      half4 ov = {(_Float16)(((float)hv[0] - mean) * rs * g4.x + b4.x),
                  (_Float16)(((float)hv[1] - mean) * rs * g4.y + b4.y),
                  (_Float16)(((float)hv[2] - mean) * rs * g4.z + b4.z),
                  (_Float16)(((float)hv[3] - mean) * rs * g4.w + b4.w)};
      *(half4*)(bufA + byte) = ov;
    }
  }
  __syncthreads();

  {  // fc1: bufA @ wf1 -> LN2 -> bufA (in-place)
    f32x4 acc[4][4];
    init_accn<4>(bf1, 0, acc, tid);
    do_slice<512, 0, 16, 512, 4>(wf1t, bufA, 0, acc, tid);
    epi_ln_store(acc, bufA, st1, st2, stM, stR, g2, be2, tid);
  }
  {  // fc2: bufA @ wf2 -> LN3 -> bufA (in-place)
    f32x4 acc[4][4];
    init_accn<4>(bf2, 0, acc, tid);
    do_slice<512, 0, 16, 512, 4>(wf2t, bufA, 0, acc, tid);
    epi_ln_store(acc, bufA, st1, st2, stM, stR, g3, be3, tid);
  }
  {  // fc3: bufA @ wf3 [64x512]@[512x16], 4-wave M-split, direct store
    const int w = tid >> 6, lane = tid & 63, ln15 = lane & 15, kg = lane >> 4;
    if (w < 4) {
      f32x4 acc3 = {0.f, 0.f, 0.f, 0.f};
#pragma unroll
      for (int c = 0; c < 16; ++c) {
        half8 b = *(const half8*)((const char*)wf3t + ln15 * 1024 + c * 64 + kg * 16);
        int row = w * 16 + ln15;
        half8 a = *(const half8*)(bufA + ((row * 1024 + c * 64 + kg * 16) ^ ((row & 7) << 4)));
        acc3 = __builtin_amdgcn_mfma_f32_16x16x32_f16(a, b, acc3, 0, 0, 0);
      }
#pragma unroll
      for (int j = 0; j < 4; ++j)
        x3[(size_t)(r0 + w * 16 + kg * 4 + j) * 16 + ln15] = acc3[j] + bf3[ln15];
    }
  }
}

// ---------------- triu mask + symmetrize ----------------
__global__ void k_sym(const float* __restrict__ x3, float* __restrict__ out) {
  int t = blockIdx.x * 256 + threadIdx.x;
  if (t >= SEGN * 4) return;
  int q = t & 3;
  int cell = t >> 2;
  int j = cell % Nn;
  int tmp = cell / Nn;
  int i = tmp % Nn;
  int b = tmp / Nn;
  float4 v = make_float4(0.f, 0.f, 0.f, 0.f);
  if (i <= j) v = *(const float4*)&x3[(size_t)cell * 16 + q * 4];
  if (j <= i) {
    int cell2 = (b * Nn + j) * Nn + i;
    float4 u = *(const float4*)&x3[(size_t)cell2 * 16 + q * 4];
    v.x += u.x; v.y += u.y; v.z += u.z; v.w += u.w;
  }
  *(float4*)&out[(size_t)t * 4] = v;
}

extern "C" void kernel_launch(void* const* d_in, const int* in_sizes, int n_in,
                              void* d_out, int out_size, void* d_ws, size_t ws_size,
                              hipStream_t stream) {
  const int*   rel_type  = (const int*)d_in[0];
  const float* rel_error = (const float*)d_in[1];
  const int*   edge_pos  = (const int*)d_in[2];
  const int*   dist      = (const int*)d_in[3];
  const int*   rel_row   = (const int*)d_in[4];
  const float* type_tab = (const float*)d_in[8];
  const float* pos_tab  = (const float*)d_in[9];
  const float* dist_tab = (const float*)d_in[10];
  const float* w1 = (const float*)d_in[11]; const float* b1 = (const float*)d_in[12];
  const float* w2 = (const float*)d_in[13]; const float* b2 = (const float*)d_in[14];
  const float* w3 = (const float*)d_in[15]; const float* b3 = (const float*)d_in[16];
  const float* g1 = (const float*)d_in[17]; const float* be1 = (const float*)d_in[18];
  const float* wf1 = (const float*)d_in[19]; const float* bf1 = (const float*)d_in[20];
  const float* g2 = (const float*)d_in[21]; const float* be2 = (const float*)d_in[22];
  const float* wf2 = (const float*)d_in[23]; const float* bf2 = (const float*)d_in[24];
  const float* g3 = (const float*)d_in[25]; const float* be3 = (const float*)d_in[26];
  const float* wf3 = (const float*)d_in[27]; const float* bf3 = (const float*)d_in[28];

  const int E = in_sizes[0];
  const size_t seg_bytes = (size_t)SEGN * 512 * 4;     // 209.7 MB
  const size_t x3_bytes  = (size_t)SEGN * 16 * 4;      // 6.55 MB
  const size_t wt_elems  = 32768 + 131072 + 262144 * 3 + 8192;
  if (ws_size < seg_bytes + x3_bytes + wt_elems * 2) return;

  unsigned*  seg = (unsigned*)d_ws;
  float*     x3  = (float*)((char*)d_ws + seg_bytes);
  _Float16*  w1t = (_Float16*)((char*)d_ws + seg_bytes + x3_bytes);
  _Float16*  w2t = w1t + 32768;
  _Float16*  w3t = w2t + 131072;
  _Float16*  wf1t = w3t + 262144;
  _Float16*  wf2t = wf1t + 262144;
  _Float16*  wf3t = wf2t + 262144;
  float*     out = (float*)d_out;

  k_prep<<<3744, 256, 0, stream>>>(w1, w2, w3, wf1, wf2, wf3,
                                   w1t, w2t, w3t, wf1t, wf2t, wf3t);
  k_init<<<2048, 256, 0, stream>>>((uint4*)seg, SEGN * 512 / 4);
  k_edge<<<(E + 63) / 64, 512, 0, stream>>>(rel_type, rel_error, edge_pos, rel_row,
                                            type_tab, pos_tab, w1t, b1, w2t, b2, w3t, b3,
                                            seg, E);
  k_fc<<<SEGN / 64, 512, 0, stream>>>(seg, dist, dist_tab,
                                      g1, be1, wf1t, bf1,
                                      g2, be2, wf2t, bf2,
                                      g3, be3, wf3t, bf3, x3);
  k_sym<<<(SEGN * 4 + 255) / 256, 256, 0, stream>>>(x3, out);
}